// Round 1
// baseline (116.009 us; speedup 1.0000x reference)
//
#include <hip/hip_runtime.h>

// FeatureWithRelativePosition: fused pairwise-dist -> Linear(4096->64) -> LN -> SiLU
// BS=4, N=4096, FEAT=64. fp32 in/out, bf16 MFMA inner product, fp32 accumulate.

typedef float f32x4 __attribute__((ext_vector_type(4)));
typedef __bf16 bf16x8 __attribute__((ext_vector_type(8)));

union BF8 { bf16x8 v; uint4 u; };

#define N_PTS 4096
#define FEATD 64
#define TM 64          // rows per block
#define BK 256         // K-chunk staged per iteration
#define NCHUNK (N_PTS / BK)

// ---- pre-pass: W fp32 -> bf16 row-major [64][4096] into workspace ----
__global__ void wconv_kernel(const float* __restrict__ W,
                             unsigned short* __restrict__ Wb) {
  int gid = blockIdx.x * blockDim.x + threadIdx.x;  // 32768 threads, 8 elems each
  const float4* W4 = (const float4*)W;
  float4 a = W4[gid * 2];
  float4 b = W4[gid * 2 + 1];
  BF8 o;
  o.v[0] = (__bf16)a.x; o.v[1] = (__bf16)a.y; o.v[2] = (__bf16)a.z; o.v[3] = (__bf16)a.w;
  o.v[4] = (__bf16)b.x; o.v[5] = (__bf16)b.y; o.v[6] = (__bf16)b.z; o.v[7] = (__bf16)b.w;
  ((uint4*)Wb)[gid] = o.u;
}

// ---- main fused kernel ----
// grid = 256 blocks (batch = bid>>6, row tile = (bid&63)*64), block = 512 thr (8 waves)
// wave&3 = rowgroup (16 rows), wave>>2 = K-half (2048 each), merged via LDS.
__global__ __launch_bounds__(512, 2) void frp_kernel(
    const float* __restrict__ pos, const float* __restrict__ W,
    const float* __restrict__ bias, const float* __restrict__ gamma,
    const float* __restrict__ beta, const unsigned short* __restrict__ Wb,
    float* __restrict__ out) {
  // W tile [64 f][256 m] bf16, stored as 16B granules with XOR swizzle (2-way max conflict)
  __shared__ uint4 Wlds[64 * 32];   // 32 KiB
  __shared__ float4 Plds[288];      // 256 points + pad every 8 (bank spread)

  const int tid = threadIdx.x;
  const int lane = tid & 63;
  const int wave = tid >> 6;
  const int rowgroup = wave & 3;
  const int khalf = wave >> 2;
  const int fx = lane & 15;
  const int q = lane >> 4;

  const int batch = blockIdx.x >> 6;
  const int nb = (blockIdx.x & 63) * TM;

  const float* posB = pos + (size_t)batch * N_PTS * 3;

  // this lane's A-row (n) position: A-frag row = lane&15
  const int nrow = nb + rowgroup * 16 + fx;
  const float px = posB[nrow * 3 + 0];
  const float py = posB[nrow * 3 + 1];
  const float pz = posB[nrow * 3 + 2];

  f32x4 acc[4];
#pragma unroll
  for (int t = 0; t < 4; ++t) acc[t] = (f32x4){0.f, 0.f, 0.f, 0.f};

  const bool useWb = (Wb != nullptr);

  for (int c = 0; c < NCHUNK; ++c) {
    __syncthreads();
    // stage positions for this m-chunk (threads 0..255)
    if (tid < BK) {
      int m = c * BK + tid;
      Plds[tid + (tid >> 3)] =
          make_float4(posB[m * 3], posB[m * 3 + 1], posB[m * 3 + 2], 0.f);
    }
    // stage W tile: 2048 granules of 16B, 512 threads -> 4 iters
#pragma unroll
    for (int it = 0; it < 4; ++it) {
      int gi = it * 512 + tid;
      int f = gi >> 5, g = gi & 31;
      uint4 val;
      if (useWb) {
        val = *(const uint4*)(Wb + (size_t)f * N_PTS + c * BK + g * 8);
      } else {
        const float4* src = (const float4*)(W + (size_t)f * N_PTS + c * BK + g * 8);
        float4 a = src[0], b2 = src[1];
        BF8 o;
        o.v[0] = (__bf16)a.x;  o.v[1] = (__bf16)a.y;  o.v[2] = (__bf16)a.z;  o.v[3] = (__bf16)a.w;
        o.v[4] = (__bf16)b2.x; o.v[5] = (__bf16)b2.y; o.v[6] = (__bf16)b2.z; o.v[7] = (__bf16)b2.w;
        val = o.u;
      }
      Wlds[f * 32 + ((g & 16) | ((g ^ f) & 15))] = val;
    }
    __syncthreads();

#pragma unroll
    for (int ks = 0; ks < 4; ++ks) {
      const int g8 = khalf * 16 + ks * 4 + q;  // this lane's 8-pt granule index
      const int mloc = g8 * 8;
      float4 p[8];
#pragma unroll
      for (int j = 0; j < 8; ++j) p[j] = Plds[mloc + j + g8];  // +g8 = pad offset
      // A-frag: 8 distances in registers (row=lane&15, k=q*8+j)
      bf16x8 af;
#pragma unroll
      for (int j = 0; j < 8; ++j) {
        float dx = px - p[j].x, dy = py - p[j].y, dz = pz - p[j].z;
        float sq = dx * dx + dy * dy + dz * dz;
        af[j] = (__bf16)__builtin_amdgcn_sqrtf(sq);  // sqrt(0)=0 matches ref's where()
      }
      // B-frags from swizzled LDS (B[k=q*8+j][f=lane&15]) + 4 MFMAs
#pragma unroll
      for (int t = 0; t < 4; ++t) {
        int f = t * 16 + fx;
        BF8 bw;
        bw.u = Wlds[f * 32 + ((g8 & 16) | ((g8 ^ f) & 15))];
        acc[t] = __builtin_amdgcn_mfma_f32_16x16x32_bf16(af, bw.v, acc[t], 0, 0, 0);
      }
    }
  }

  // ---- merge K-halves via LDS (reuse Wlds) ----
  __syncthreads();
  f32x4* mbuf = (f32x4*)Wlds;  // 16 KiB < 32 KiB
  if (khalf == 1) {
#pragma unroll
    for (int t = 0; t < 4; ++t) mbuf[(rowgroup * 64 + lane) * 4 + t] = acc[t];
  }
  __syncthreads();
  if (khalf == 0) {
#pragma unroll
    for (int t = 0; t < 4; ++t) acc[t] += mbuf[(rowgroup * 64 + lane) * 4 + t];

    // epilogue: bias + LayerNorm(over 64 feats) + SiLU
    // C/D layout: col(f within tile)=lane&15, row(n local)=q*4+reg
    float bb[4], gg[4], be[4];
#pragma unroll
    for (int t = 0; t < 4; ++t) {
      bb[t] = bias[t * 16 + fx];
      gg[t] = gamma[t * 16 + fx];
      be[t] = beta[t * 16 + fx];
    }
    float* outB = out + ((size_t)batch * N_PTS + nb + rowgroup * 16) * FEATD;
#pragma unroll
    for (int r = 0; r < 4; ++r) {
      float x[4], d[4];
#pragma unroll
      for (int t = 0; t < 4; ++t) x[t] = acc[t][r] + bb[t];
      float s = x[0] + x[1] + x[2] + x[3];
      s += __shfl_xor(s, 1); s += __shfl_xor(s, 2);
      s += __shfl_xor(s, 4); s += __shfl_xor(s, 8);  // reduce over 16 lanes of quad
      float mu = s * (1.f / 64.f);
      float v = 0.f;
#pragma unroll
      for (int t = 0; t < 4; ++t) { d[t] = x[t] - mu; v += d[t] * d[t]; }
      v += __shfl_xor(v, 1); v += __shfl_xor(v, 2);
      v += __shfl_xor(v, 4); v += __shfl_xor(v, 8);
      float rstd = __builtin_amdgcn_rsqf(v * (1.f / 64.f) + 1e-5f);
      float* orow = outB + (q * 4 + r) * FEATD;
#pragma unroll
      for (int t = 0; t < 4; ++t) {
        float xn = d[t] * rstd * gg[t] + be[t];
        float y = xn * (1.f / (1.f + __expf(-xn)));  // SiLU
        orow[t * 16 + fx] = y;
      }
    }
  }
}

extern "C" void kernel_launch(void* const* d_in, const int* in_sizes, int n_in,
                              void* d_out, int out_size, void* d_ws, size_t ws_size,
                              hipStream_t stream) {
  const float* pos   = (const float*)d_in[0];  // (4,4096,3)
  const float* W     = (const float*)d_in[1];  // (64,4096)
  const float* bias  = (const float*)d_in[2];  // (64,)
  const float* gamma = (const float*)d_in[3];  // (64,)
  const float* beta  = (const float*)d_in[4];  // (64,)
  float* out = (float*)d_out;                  // (4,4096,64)

  const size_t wb_bytes = (size_t)FEATD * N_PTS * sizeof(unsigned short);  // 512 KiB
  int use_ws = (d_ws != nullptr && ws_size >= wb_bytes);
  unsigned short* Wb = use_ws ? (unsigned short*)d_ws : nullptr;

  if (use_ws) {
    wconv_kernel<<<dim3((FEATD * N_PTS / 8) / 256), dim3(256), 0, stream>>>(W, Wb);
  }
  frp_kernel<<<dim3(256), dim3(512), 0, stream>>>(pos, W, bias, gamma, beta, Wb, out);
}

// Round 2
// 106.532 us; speedup vs baseline: 1.0890x; 1.0890x over previous
//
#include <hip/hip_runtime.h>

// FeatureWithRelativePosition: fused pairwise-dist -> Linear(4096->64) -> LN -> SiLU
// BS=4, N=4096, FEAT=64. fp32 in/out, bf16 MFMA inner product, fp32 accumulate.
//
// R2: 1024-thr blocks (16 waves: 4 rowgroups x 4 K-splits) = 4 waves/SIMD.
//     Positions staged SoA in LDS once; W tile double-buffered via
//     global_load_lds (16B); 1 barrier/chunk. LDS = 64 KiB W + 48 KiB pos.

typedef float f32x4 __attribute__((ext_vector_type(4)));
typedef __bf16 bf16x8 __attribute__((ext_vector_type(8)));

union BF8 { bf16x8 v; uint4 u; };

#define N_PTS 4096
#define FEATD 64
#define BK 256
#define NCH (N_PTS / BK)

// ---- pre-pass: W fp32 -> bf16 row-major [64][4096] into workspace ----
__global__ void wconv_kernel(const float* __restrict__ W,
                             unsigned short* __restrict__ Wb) {
  int gid = blockIdx.x * blockDim.x + threadIdx.x;  // 32768 threads, 8 elems each
  const float4* W4 = (const float4*)W;
  float4 a = W4[gid * 2];
  float4 b = W4[gid * 2 + 1];
  BF8 o;
  o.v[0] = (__bf16)a.x; o.v[1] = (__bf16)a.y; o.v[2] = (__bf16)a.z; o.v[3] = (__bf16)a.w;
  o.v[4] = (__bf16)b.x; o.v[5] = (__bf16)b.y; o.v[6] = (__bf16)b.z; o.v[7] = (__bf16)b.w;
  ((uint4*)Wb)[gid] = o.u;
}

__device__ __forceinline__ void load_lds16(const void* g, void* l) {
  __builtin_amdgcn_global_load_lds(
      (const __attribute__((address_space(1))) void*)g,
      (__attribute__((address_space(3))) void*)l, 16, 0, 0);
}

// grid = 256 blocks (batch = bid>>6, rowtile = (bid&63)*64), block = 1024 thr.
// wave&3 = rowgroup (16 rows each), wave>>2 = khalf (K quarter within each chunk).
__global__ __launch_bounds__(1024, 4) void frp_kernel(
    const float* __restrict__ pos, const float* __restrict__ W,
    const float* __restrict__ bias, const float* __restrict__ gamma,
    const float* __restrict__ beta, const unsigned short* __restrict__ Wb,
    float* __restrict__ out) {
  __shared__ uint4 Wbuf[2][2048];                       // 64 KiB: [buf][f*32+g]
  __shared__ __align__(16) float Px[N_PTS];             // 16 KiB each, SoA
  __shared__ __align__(16) float Py[N_PTS];
  __shared__ __align__(16) float Pz[N_PTS];

  const int tid = threadIdx.x;
  const int lane = tid & 63;
  const int wave = tid >> 6;
  const int rowgroup = wave & 3;
  const int khalf = wave >> 2;     // 0..3
  const int fx = lane & 15;
  const int q = lane >> 4;

  const int batch = blockIdx.x >> 6;
  const int nb = (blockIdx.x & 63) * 64;
  const float* posB = pos + (size_t)batch * N_PTS * 3;

  // ---- stage ALL positions SoA (once). 1024 thr x 4 pts, float4 in/out. ----
  {
    const float4* p4 = (const float4*)posB;
    float4 f0 = p4[tid * 3 + 0];
    float4 f1 = p4[tid * 3 + 1];
    float4 f2 = p4[tid * 3 + 2];
    ((float4*)Px)[tid] = make_float4(f0.x, f0.w, f1.z, f2.y);
    ((float4*)Py)[tid] = make_float4(f0.y, f1.x, f1.w, f2.z);
    ((float4*)Pz)[tid] = make_float4(f0.z, f1.y, f2.x, f2.w);
  }

  const bool useWb = (Wb != nullptr);

  // ---- W chunk staging: 2048 x 16B granules, layout Wbuf[b][f*32+g] ----
  auto stageW = [&](int c, int b) {
#pragma unroll
    for (int it = 0; it < 2; ++it) {
      int gi = it * 1024 + tid;
      int f = gi >> 5, g = gi & 31;
      if (useWb) {
        const unsigned short* src = Wb + (size_t)f * N_PTS + c * BK + g * 8;
        load_lds16(src, &Wbuf[b][gi]);   // lane-linear LDS dest (wave base + lane*16)
      } else {
        const float4* src = (const float4*)(W + (size_t)f * N_PTS + c * BK + g * 8);
        float4 a = src[0], b2 = src[1];
        BF8 o;
        o.v[0] = (__bf16)a.x;  o.v[1] = (__bf16)a.y;  o.v[2] = (__bf16)a.z;  o.v[3] = (__bf16)a.w;
        o.v[4] = (__bf16)b2.x; o.v[5] = (__bf16)b2.y; o.v[6] = (__bf16)b2.z; o.v[7] = (__bf16)b2.w;
        Wbuf[b][gi] = o.u;
      }
    }
  };

  f32x4 acc[4];
#pragma unroll
  for (int t = 0; t < 4; ++t) acc[t] = (f32x4){0.f, 0.f, 0.f, 0.f};

  stageW(0, 0);
  __syncthreads();   // drains pos staging + first W tile

  // this lane's A-row position (from LDS, 16-way broadcast)
  const int nrow = nb + rowgroup * 16 + fx;
  const float px = Px[nrow], py = Py[nrow], pz = Pz[nrow];

  for (int c = 0; c < NCH; ++c) {
    if (c + 1 < NCH) stageW(c + 1, (c + 1) & 1);  // DMA next tile; stays in flight
    const uint4* Wcur = Wbuf[c & 1];
#pragma unroll
    for (int ks = 0; ks < 2; ++ks) {
      const int g8 = khalf * 8 + ks * 4 + q;      // granule (8 pts) within chunk
      const int m4 = c * 64 + g8 * 2;             // f32x4 index into SoA arrays
      f32x4 xa = ((const f32x4*)Px)[m4], xb = ((const f32x4*)Px)[m4 + 1];
      f32x4 ya = ((const f32x4*)Py)[m4], yb = ((const f32x4*)Py)[m4 + 1];
      f32x4 za = ((const f32x4*)Pz)[m4], zb = ((const f32x4*)Pz)[m4 + 1];
      f32x4 dxa = xa - px, dya = ya - py, dza = za - pz;
      f32x4 dxb = xb - px, dyb = yb - py, dzb = zb - pz;
      f32x4 sqa = dxa * dxa + dya * dya + dza * dza;
      f32x4 sqb = dxb * dxb + dyb * dyb + dzb * dzb;
      bf16x8 af;
#pragma unroll
      for (int j = 0; j < 4; ++j) af[j] = (__bf16)__builtin_amdgcn_sqrtf(sqa[j]);
#pragma unroll
      for (int j = 0; j < 4; ++j) af[4 + j] = (__bf16)__builtin_amdgcn_sqrtf(sqb[j]);
#pragma unroll
      for (int t = 0; t < 4; ++t) {
        BF8 bw;
        bw.u = Wcur[(t * 16 + fx) * 32 + g8];     // 4 lines/wave, 16x broadcast: conflict-free
        acc[t] = __builtin_amdgcn_mfma_f32_16x16x32_bf16(af, bw.v, acc[t], 0, 0, 0);
      }
    }
    __syncthreads();  // drains next-tile DMA (already landed during compute) + buffer swap
  }

  // ---- merge K-quarters via LDS (reuse Wbuf: 48 KiB needed <= 64 KiB) ----
  float* mb = (float*)Wbuf;
  const int lslot = rowgroup * 64 + lane;  // 0..255
  if (khalf > 0) {
#pragma unroll
    for (int t = 0; t < 4; ++t)
#pragma unroll
      for (int r = 0; r < 4; ++r)
        mb[(khalf - 1) * 4096 + (t * 4 + r) * 256 + lslot] = acc[t][r];
  }
  __syncthreads();
  if (khalf == 0) {
#pragma unroll
    for (int s = 0; s < 3; ++s)
#pragma unroll
      for (int t = 0; t < 4; ++t)
#pragma unroll
        for (int r = 0; r < 4; ++r)
          acc[t][r] += mb[s * 4096 + (t * 4 + r) * 256 + lslot];

    // epilogue: bias + LayerNorm(64) + SiLU. C/D layout: col=lane&15, row=q*4+r.
    float bb[4], gg[4], be[4];
#pragma unroll
    for (int t = 0; t < 4; ++t) {
      bb[t] = bias[t * 16 + fx];
      gg[t] = gamma[t * 16 + fx];
      be[t] = beta[t * 16 + fx];
    }
    float* outB = out + ((size_t)batch * N_PTS + nb + rowgroup * 16) * FEATD;
#pragma unroll
    for (int r = 0; r < 4; ++r) {
      float x[4], d[4];
#pragma unroll
      for (int t = 0; t < 4; ++t) x[t] = acc[t][r] + bb[t];
      float s = x[0] + x[1] + x[2] + x[3];
      s += __shfl_xor(s, 1); s += __shfl_xor(s, 2);
      s += __shfl_xor(s, 4); s += __shfl_xor(s, 8);
      float mu = s * (1.f / 64.f);
      float v = 0.f;
#pragma unroll
      for (int t = 0; t < 4; ++t) { d[t] = x[t] - mu; v += d[t] * d[t]; }
      v += __shfl_xor(v, 1); v += __shfl_xor(v, 2);
      v += __shfl_xor(v, 4); v += __shfl_xor(v, 8);
      float rstd = __builtin_amdgcn_rsqf(v * (1.f / 64.f) + 1e-5f);
      float* orow = outB + (q * 4 + r) * FEATD;
#pragma unroll
      for (int t = 0; t < 4; ++t) {
        float xn = d[t] * rstd * gg[t] + be[t];
        float y = xn * (1.f / (1.f + __expf(-xn)));  // SiLU
        orow[t * 16 + fx] = y;
      }
    }
  }
}

extern "C" void kernel_launch(void* const* d_in, const int* in_sizes, int n_in,
                              void* d_out, int out_size, void* d_ws, size_t ws_size,
                              hipStream_t stream) {
  const float* pos   = (const float*)d_in[0];  // (4,4096,3)
  const float* W     = (const float*)d_in[1];  // (64,4096)
  const float* bias  = (const float*)d_in[2];  // (64,)
  const float* gamma = (const float*)d_in[3];  // (64,)
  const float* beta  = (const float*)d_in[4];  // (64,)
  float* out = (float*)d_out;                  // (4,4096,64)

  const size_t wb_bytes = (size_t)FEATD * N_PTS * sizeof(unsigned short);  // 512 KiB
  int use_ws = (d_ws != nullptr && ws_size >= wb_bytes);
  unsigned short* Wb = use_ws ? (unsigned short*)d_ws : nullptr;

  if (use_ws) {
    wconv_kernel<<<dim3((FEATD * N_PTS / 8) / 256), dim3(256), 0, stream>>>(W, Wb);
  }
  frp_kernel<<<dim3(256), dim3(1024), 0, stream>>>(pos, W, bias, gamma, beta, Wb, out);
}

// Round 3
// 88.384 us; speedup vs baseline: 1.3126x; 1.2053x over previous
//
#include <hip/hip_runtime.h>

// FeatureWithRelativePosition: fused pairwise-dist -> Linear(4096->64) -> LN -> SiLU
// BS=4, N=4096, FEAT=64. fp32 in/out, bf16 MFMA inner product, fp32 accumulate.
//
// R3: workspace pre-transposed to granule-major Wbt[G][f][8] so the LDS W tile
//     is [g][f] -> B-frag reads are bank-conflict-free AND staging is a
//     contiguous lane-linear global_load_lds copy. (R2's [f][g] layout put all
//     16 lanes of a quad on one 4-bank group: 14.7M conflict-cycles.)

typedef float f32x4 __attribute__((ext_vector_type(4)));
typedef __bf16 bf16x8 __attribute__((ext_vector_type(8)));

union BF8 { bf16x8 v; uint4 u; };

#define N_PTS 4096
#define FEATD 64
#define BK 256
#define NCH (N_PTS / BK)

// ---- pre-pass: W fp32 [64][4096] -> bf16 granule-major Wbt[512][64][8] ----
// uint4 slot (G*64 + f) holds W[f][G*8 .. G*8+7] as bf16.
__global__ void wconv_kernel(const float* __restrict__ W,
                             unsigned short* __restrict__ Wbt) {
  int gid = blockIdx.x * blockDim.x + threadIdx.x;  // 32768 = 64 f * 512 G
  int f = gid >> 9, m8 = gid & 511;
  const float4* src = (const float4*)(W + (size_t)f * N_PTS + m8 * 8);
  float4 a = src[0], b = src[1];   // coalesced reads (consecutive lanes -> consecutive m8)
  BF8 o;
  o.v[0] = (__bf16)a.x; o.v[1] = (__bf16)a.y; o.v[2] = (__bf16)a.z; o.v[3] = (__bf16)a.w;
  o.v[4] = (__bf16)b.x; o.v[5] = (__bf16)b.y; o.v[6] = (__bf16)b.z; o.v[7] = (__bf16)b.w;
  ((uint4*)Wbt)[(size_t)m8 * 64 + f] = o.u;        // scattered 16B writes, L2-combined
}

__device__ __forceinline__ void load_lds16(const void* g, void* l) {
  __builtin_amdgcn_global_load_lds(
      (const __attribute__((address_space(1))) void*)g,
      (__attribute__((address_space(3))) void*)l, 16, 0, 0);
}

// grid = 256 blocks (batch = bid>>6, rowtile = (bid&63)*64), block = 1024 thr.
// wave&3 = rowgroup (16 rows each), wave>>2 = khalf (K quarter within chunk).
__global__ __launch_bounds__(1024, 4) void frp_kernel(
    const float* __restrict__ pos, const float* __restrict__ W,
    const float* __restrict__ bias, const float* __restrict__ gamma,
    const float* __restrict__ beta, const unsigned short* __restrict__ Wbt,
    float* __restrict__ out) {
  __shared__ uint4 Wbuf[2][2048];            // 64 KiB: slot = g*64 + f  (g = granule in chunk)
  __shared__ __align__(16) float Px[N_PTS];  // 16 KiB each, SoA
  __shared__ __align__(16) float Py[N_PTS];
  __shared__ __align__(16) float Pz[N_PTS];

  const int tid = threadIdx.x;
  const int lane = tid & 63;
  const int wave = tid >> 6;
  const int rowgroup = wave & 3;
  const int khalf = wave >> 2;     // 0..3
  const int fx = lane & 15;
  const int q = lane >> 4;

  const int batch = blockIdx.x >> 6;
  const int nb = (blockIdx.x & 63) * 64;
  const float* posB = pos + (size_t)batch * N_PTS * 3;

  // ---- stage ALL positions SoA (once). 1024 thr x 4 pts, float4 in/out. ----
  {
    const float4* p4 = (const float4*)posB;
    float4 f0 = p4[tid * 3 + 0];
    float4 f1 = p4[tid * 3 + 1];
    float4 f2 = p4[tid * 3 + 2];
    ((float4*)Px)[tid] = make_float4(f0.x, f0.w, f1.z, f2.y);
    ((float4*)Py)[tid] = make_float4(f0.y, f1.x, f1.w, f2.z);
    ((float4*)Pz)[tid] = make_float4(f0.z, f1.y, f2.x, f2.w);
  }

  const bool useWb = (Wbt != nullptr);

  // ---- W chunk staging: 2048 consecutive uint4s (granule-major) ----
  auto stageW = [&](int c, int b) {
#pragma unroll
    for (int it = 0; it < 2; ++it) {
      int gi = it * 1024 + tid;
      if (useWb) {
        load_lds16(Wbt + ((size_t)c * 2048 + gi) * 8, &Wbuf[b][gi]);
      } else {
        // fallback: build granule-major tile from fp32 W (uncoalesced, rare path)
        int g = gi >> 6, f = gi & 63;
        const float4* src = (const float4*)(W + (size_t)f * N_PTS + c * BK + g * 8);
        float4 a = src[0], b2 = src[1];
        BF8 o;
        o.v[0] = (__bf16)a.x;  o.v[1] = (__bf16)a.y;  o.v[2] = (__bf16)a.z;  o.v[3] = (__bf16)a.w;
        o.v[4] = (__bf16)b2.x; o.v[5] = (__bf16)b2.y; o.v[6] = (__bf16)b2.z; o.v[7] = (__bf16)b2.w;
        Wbuf[b][gi] = o.u;
      }
    }
  };

  f32x4 acc[4];
#pragma unroll
  for (int t = 0; t < 4; ++t) acc[t] = (f32x4){0.f, 0.f, 0.f, 0.f};

  stageW(0, 0);
  __syncthreads();   // drains pos staging + first W tile

  // this lane's A-row position (from LDS, broadcast within quad)
  const int nrow = nb + rowgroup * 16 + fx;
  const float px = Px[nrow], py = Py[nrow], pz = Pz[nrow];

  for (int c = 0; c < NCH; ++c) {
    if (c + 1 < NCH) stageW(c + 1, (c + 1) & 1);  // DMA next tile; stays in flight
    const uint4* Wcur = Wbuf[c & 1];
#pragma unroll
    for (int ks = 0; ks < 2; ++ks) {
      const int g8 = khalf * 8 + ks * 4 + q;      // granule (8 pts) within chunk
      const int m4 = c * 64 + g8 * 2;             // f32x4 index into SoA arrays
      f32x4 xa = ((const f32x4*)Px)[m4], xb = ((const f32x4*)Px)[m4 + 1];
      f32x4 ya = ((const f32x4*)Py)[m4], yb = ((const f32x4*)Py)[m4 + 1];
      f32x4 za = ((const f32x4*)Pz)[m4], zb = ((const f32x4*)Pz)[m4 + 1];
      f32x4 dxa = xa - px, dya = ya - py, dza = za - pz;
      f32x4 dxb = xb - px, dyb = yb - py, dzb = zb - pz;
      f32x4 sqa = dxa * dxa + dya * dya + dza * dza;
      f32x4 sqb = dxb * dxb + dyb * dyb + dzb * dzb;
      bf16x8 af;
#pragma unroll
      for (int j = 0; j < 4; ++j) af[j] = (__bf16)__builtin_amdgcn_sqrtf(sqa[j]);
#pragma unroll
      for (int j = 0; j < 4; ++j) af[4 + j] = (__bf16)__builtin_amdgcn_sqrtf(sqb[j]);
#pragma unroll
      for (int t = 0; t < 4; ++t) {
        BF8 bw;
        // slot = g8*64 + f: slot%8 == fx%8 -> every 8-lane group spans all 32 banks
        bw.u = Wcur[g8 * 64 + t * 16 + fx];
        acc[t] = __builtin_amdgcn_mfma_f32_16x16x32_bf16(af, bw.v, acc[t], 0, 0, 0);
      }
    }
    __syncthreads();  // next-tile DMA already landed during compute; swap buffers
  }

  // ---- merge K-quarters via LDS (reuse Wbuf: 48 KiB needed <= 64 KiB) ----
  float* mb = (float*)Wbuf;
  const int lslot = rowgroup * 64 + lane;  // 0..255
  if (khalf > 0) {
#pragma unroll
    for (int t = 0; t < 4; ++t)
#pragma unroll
      for (int r = 0; r < 4; ++r)
        mb[(khalf - 1) * 4096 + (t * 4 + r) * 256 + lslot] = acc[t][r];
  }
  __syncthreads();
  if (khalf == 0) {
#pragma unroll
    for (int s = 0; s < 3; ++s)
#pragma unroll
      for (int t = 0; t < 4; ++t)
#pragma unroll
        for (int r = 0; r < 4; ++r)
          acc[t][r] += mb[s * 4096 + (t * 4 + r) * 256 + lslot];

    // epilogue: bias + LayerNorm(64) + SiLU. C/D layout: col=lane&15, row=q*4+r.
    float bb[4], gg[4], be[4];
#pragma unroll
    for (int t = 0; t < 4; ++t) {
      bb[t] = bias[t * 16 + fx];
      gg[t] = gamma[t * 16 + fx];
      be[t] = beta[t * 16 + fx];
    }
    float* outB = out + ((size_t)batch * N_PTS + nb + rowgroup * 16) * FEATD;
#pragma unroll
    for (int r = 0; r < 4; ++r) {
      float x[4], d[4];
#pragma unroll
      for (int t = 0; t < 4; ++t) x[t] = acc[t][r] + bb[t];
      float s = x[0] + x[1] + x[2] + x[3];
      s += __shfl_xor(s, 1); s += __shfl_xor(s, 2);
      s += __shfl_xor(s, 4); s += __shfl_xor(s, 8);
      float mu = s * (1.f / 64.f);
      float v = 0.f;
#pragma unroll
      for (int t = 0; t < 4; ++t) { d[t] = x[t] - mu; v += d[t] * d[t]; }
      v += __shfl_xor(v, 1); v += __shfl_xor(v, 2);
      v += __shfl_xor(v, 4); v += __shfl_xor(v, 8);
      float rstd = __builtin_amdgcn_rsqf(v * (1.f / 64.f) + 1e-5f);
      float* orow = outB + (q * 4 + r) * FEATD;
#pragma unroll
      for (int t = 0; t < 4; ++t) {
        float xn = d[t] * rstd * gg[t] + be[t];
        float y = xn * (1.f / (1.f + __expf(-xn)));  // SiLU
        orow[t * 16 + fx] = y;
      }
    }
  }
}

extern "C" void kernel_launch(void* const* d_in, const int* in_sizes, int n_in,
                              void* d_out, int out_size, void* d_ws, size_t ws_size,
                              hipStream_t stream) {
  const float* pos   = (const float*)d_in[0];  // (4,4096,3)
  const float* W     = (const float*)d_in[1];  // (64,4096)
  const float* bias  = (const float*)d_in[2];  // (64,)
  const float* gamma = (const float*)d_in[3];  // (64,)
  const float* beta  = (const float*)d_in[4];  // (64,)
  float* out = (float*)d_out;                  // (4,4096,64)

  const size_t wb_bytes = (size_t)FEATD * N_PTS * sizeof(unsigned short);  // 512 KiB
  int use_ws = (d_ws != nullptr && ws_size >= wb_bytes);
  unsigned short* Wbt = use_ws ? (unsigned short*)d_ws : nullptr;

  if (use_ws) {
    wconv_kernel<<<dim3((FEATD * N_PTS / 8) / 256), dim3(256), 0, stream>>>(W, Wbt);
  }
  frp_kernel<<<dim3(256), dim3(1024), 0, stream>>>(pos, W, bias, gamma, beta, Wbt, out);
}

// Round 4
// 87.060 us; speedup vs baseline: 1.3325x; 1.0152x over previous
//
#include <hip/hip_runtime.h>

// FeatureWithRelativePosition: fused pairwise-dist -> Linear(4096->64) -> LN -> SiLU
// BS=4, N=4096, FEAT=64. fp32 in/out, bf16 MFMA inner product, fp32 accumulate.
//
// R4: wave partition 2 rowsets x 8 K-slices (was 4x4). Each wave computes 2
//     A-frags from one set of 8 staged points and reuses the 4 W-frags for
//     both -> LDS-pipe instrs per MFMA halved (10 reads : 8 MFMAs). 8-way
//     K-merge done in two LDS rounds. (R3 was LDS-pipe-bound: 320 b128/chunk
//     x 12 cyc = 25.6 us of serialized LDS.)

typedef float f32x4 __attribute__((ext_vector_type(4)));
typedef __bf16 bf16x8 __attribute__((ext_vector_type(8)));

union BF8 { bf16x8 v; uint4 u; };

#define N_PTS 4096
#define FEATD 64
#define BK 256
#define NCH (N_PTS / BK)

// ---- pre-pass: W fp32 [64][4096] -> bf16 granule-major Wbt[512][64][8] ----
// uint4 slot (G*64 + f) holds W[f][G*8 .. G*8+7] as bf16.
__global__ void wconv_kernel(const float* __restrict__ W,
                             unsigned short* __restrict__ Wbt) {
  int gid = blockIdx.x * blockDim.x + threadIdx.x;  // 32768 = 64 f * 512 G
  int f = gid >> 9, m8 = gid & 511;
  const float4* src = (const float4*)(W + (size_t)f * N_PTS + m8 * 8);
  float4 a = src[0], b = src[1];
  BF8 o;
  o.v[0] = (__bf16)a.x; o.v[1] = (__bf16)a.y; o.v[2] = (__bf16)a.z; o.v[3] = (__bf16)a.w;
  o.v[4] = (__bf16)b.x; o.v[5] = (__bf16)b.y; o.v[6] = (__bf16)b.z; o.v[7] = (__bf16)b.w;
  ((uint4*)Wbt)[(size_t)m8 * 64 + f] = o.u;
}

__device__ __forceinline__ void load_lds16(const void* g, void* l) {
  __builtin_amdgcn_global_load_lds(
      (const __attribute__((address_space(1))) void*)g,
      (__attribute__((address_space(3))) void*)l, 16, 0, 0);
}

// grid = 256 blocks (batch = bid>>6, rowtile = (bid&63)*64), block = 1024 thr.
// wave&1 = rowset (32 rows), wave>>1 = K-slice (32 k per chunk).
__global__ __launch_bounds__(1024, 4) void frp_kernel(
    const float* __restrict__ pos, const float* __restrict__ W,
    const float* __restrict__ bias, const float* __restrict__ gamma,
    const float* __restrict__ beta, const unsigned short* __restrict__ Wbt,
    float* __restrict__ out) {
  __shared__ uint4 Wbuf[2][2048];            // 64 KiB: slot = g*64 + f
  __shared__ __align__(16) float Px[N_PTS];  // 16 KiB each, SoA
  __shared__ __align__(16) float Py[N_PTS];
  __shared__ __align__(16) float Pz[N_PTS];

  const int tid = threadIdx.x;
  const int lane = tid & 63;
  const int wave = tid >> 6;
  const int rs  = wave & 1;        // rowset: rows rs*32 .. rs*32+31
  const int ksl = wave >> 1;       // 0..7: k-slice (granules ksl*4..ksl*4+3)
  const int fx = lane & 15;
  const int q = lane >> 4;

  const int batch = blockIdx.x >> 6;
  const int nb = (blockIdx.x & 63) * 64;
  const float* posB = pos + (size_t)batch * N_PTS * 3;

  // ---- stage ALL positions SoA (once). 1024 thr x 4 pts, float4 in/out. ----
  {
    const float4* p4 = (const float4*)posB;
    float4 f0 = p4[tid * 3 + 0];
    float4 f1 = p4[tid * 3 + 1];
    float4 f2 = p4[tid * 3 + 2];
    ((float4*)Px)[tid] = make_float4(f0.x, f0.w, f1.z, f2.y);
    ((float4*)Py)[tid] = make_float4(f0.y, f1.x, f1.w, f2.z);
    ((float4*)Pz)[tid] = make_float4(f0.z, f1.y, f2.x, f2.w);
  }

  const bool useWb = (Wbt != nullptr);

  // ---- W chunk staging: 2048 consecutive uint4s (granule-major) ----
  auto stageW = [&](int c, int b) {
#pragma unroll
    for (int it = 0; it < 2; ++it) {
      int gi = it * 1024 + tid;
      if (useWb) {
        load_lds16(Wbt + ((size_t)c * 2048 + gi) * 8, &Wbuf[b][gi]);
      } else {
        int g = gi >> 6, f = gi & 63;
        const float4* src = (const float4*)(W + (size_t)f * N_PTS + c * BK + g * 8);
        float4 a = src[0], b2 = src[1];
        BF8 o;
        o.v[0] = (__bf16)a.x;  o.v[1] = (__bf16)a.y;  o.v[2] = (__bf16)a.z;  o.v[3] = (__bf16)a.w;
        o.v[4] = (__bf16)b2.x; o.v[5] = (__bf16)b2.y; o.v[6] = (__bf16)b2.z; o.v[7] = (__bf16)b2.w;
        Wbuf[b][gi] = o.u;
      }
    }
  };

  f32x4 acc[2][4];
#pragma unroll
  for (int a = 0; a < 2; ++a)
#pragma unroll
    for (int t = 0; t < 4; ++t) acc[a][t] = (f32x4){0.f, 0.f, 0.f, 0.f};

  stageW(0, 0);
  __syncthreads();   // drains pos staging + first W tile

  // this lane's two A-rows (A-frag row = lane&15); read from LDS (broadcast)
  const int nrow0 = nb + rs * 32 + fx;
  const float px0 = Px[nrow0],      py0 = Py[nrow0],      pz0 = Pz[nrow0];
  const float px1 = Px[nrow0 + 16], py1 = Py[nrow0 + 16], pz1 = Pz[nrow0 + 16];

  const int g8 = ksl * 4 + q;          // this lane's granule (8 pts) within chunk

  for (int c = 0; c < NCH; ++c) {
    if (c + 1 < NCH) stageW(c + 1, (c + 1) & 1);  // DMA next tile; stays in flight
    const uint4* Wcur = Wbuf[c & 1];
    const int m4 = c * 64 + g8 * 2;               // f32x4 index into SoA arrays
    f32x4 xa = ((const f32x4*)Px)[m4], xb = ((const f32x4*)Px)[m4 + 1];
    f32x4 ya = ((const f32x4*)Py)[m4], yb = ((const f32x4*)Py)[m4 + 1];
    f32x4 za = ((const f32x4*)Pz)[m4], zb = ((const f32x4*)Pz)[m4 + 1];

    bf16x8 af0, af1;
    {
      f32x4 dx = xa - px0, dy = ya - py0, dz = za - pz0;
      f32x4 sq = dx * dx + dy * dy + dz * dz;
#pragma unroll
      for (int j = 0; j < 4; ++j) af0[j] = (__bf16)__builtin_amdgcn_sqrtf(sq[j]);
      dx = xb - px0; dy = yb - py0; dz = zb - pz0;
      sq = dx * dx + dy * dy + dz * dz;
#pragma unroll
      for (int j = 0; j < 4; ++j) af0[4 + j] = (__bf16)__builtin_amdgcn_sqrtf(sq[j]);
      dx = xa - px1; dy = ya - py1; dz = za - pz1;
      sq = dx * dx + dy * dy + dz * dz;
#pragma unroll
      for (int j = 0; j < 4; ++j) af1[j] = (__bf16)__builtin_amdgcn_sqrtf(sq[j]);
      dx = xb - px1; dy = yb - py1; dz = zb - pz1;
      sq = dx * dx + dy * dy + dz * dz;
#pragma unroll
      for (int j = 0; j < 4; ++j) af1[4 + j] = (__bf16)__builtin_amdgcn_sqrtf(sq[j]);
    }
#pragma unroll
    for (int t = 0; t < 4; ++t) {
      BF8 bw;
      bw.u = Wcur[g8 * 64 + t * 16 + fx];   // one read, two MFMAs
      acc[0][t] = __builtin_amdgcn_mfma_f32_16x16x32_bf16(af0, bw.v, acc[0][t], 0, 0, 0);
      acc[1][t] = __builtin_amdgcn_mfma_f32_16x16x32_bf16(af1, bw.v, acc[1][t], 0, 0, 0);
    }
    __syncthreads();  // next-tile DMA already landed during compute; swap buffers
  }

  // ---- 8-way K-merge via LDS (reuse Wbuf, 64 KiB = 4096 f32x4 slots) ----
  f32x4* mbv = (f32x4*)Wbuf;
  // region w (0..7): mbv[w*512 + (a*4+t)*64 + lane]
  __syncthreads();
  if (ksl >= 4) {
    int w = (ksl - 4) * 2 + rs;
#pragma unroll
    for (int a = 0; a < 2; ++a)
#pragma unroll
      for (int t = 0; t < 4; ++t)
        mbv[w * 512 + (a * 4 + t) * 64 + lane] = acc[a][t];
  }
  __syncthreads();
  if (ksl < 4) {
    int w = ksl * 2 + rs;
#pragma unroll
    for (int a = 0; a < 2; ++a)
#pragma unroll
      for (int t = 0; t < 4; ++t)
        acc[a][t] += mbv[w * 512 + (a * 4 + t) * 64 + lane];
  }
  __syncthreads();
  if (ksl >= 1 && ksl < 4) {
    int w = (ksl - 1) * 2 + rs;
#pragma unroll
    for (int a = 0; a < 2; ++a)
#pragma unroll
      for (int t = 0; t < 4; ++t)
        mbv[w * 512 + (a * 4 + t) * 64 + lane] = acc[a][t];
  }
  __syncthreads();
  if (ksl == 0) {
#pragma unroll
    for (int s = 0; s < 3; ++s)
#pragma unroll
      for (int a = 0; a < 2; ++a)
#pragma unroll
        for (int t = 0; t < 4; ++t)
          acc[a][t] += mbv[(s * 2 + rs) * 512 + (a * 4 + t) * 64 + lane];

    // epilogue: bias + LayerNorm(64) + SiLU. C/D layout: col=lane&15, row=q*4+r.
    float bb[4], gg[4], be[4];
#pragma unroll
    for (int t = 0; t < 4; ++t) {
      bb[t] = bias[t * 16 + fx];
      gg[t] = gamma[t * 16 + fx];
      be[t] = beta[t * 16 + fx];
    }
    float* outB = out + ((size_t)batch * N_PTS + nb + rs * 32) * FEATD;
#pragma unroll
    for (int a = 0; a < 2; ++a) {
#pragma unroll
      for (int r = 0; r < 4; ++r) {
        float x[4], d[4];
#pragma unroll
        for (int t = 0; t < 4; ++t) x[t] = acc[a][t][r] + bb[t];
        float s = x[0] + x[1] + x[2] + x[3];
        s += __shfl_xor(s, 1); s += __shfl_xor(s, 2);
        s += __shfl_xor(s, 4); s += __shfl_xor(s, 8);
        float mu = s * (1.f / 64.f);
        float v = 0.f;
#pragma unroll
        for (int t = 0; t < 4; ++t) { d[t] = x[t] - mu; v += d[t] * d[t]; }
        v += __shfl_xor(v, 1); v += __shfl_xor(v, 2);
        v += __shfl_xor(v, 4); v += __shfl_xor(v, 8);
        float rstd = __builtin_amdgcn_rsqf(v * (1.f / 64.f) + 1e-5f);
        float* orow = outB + (a * 16 + q * 4 + r) * FEATD;
#pragma unroll
        for (int t = 0; t < 4; ++t) {
          float xn = d[t] * rstd * gg[t] + be[t];
          float y = xn * (1.f / (1.f + __expf(-xn)));  // SiLU
          orow[t * 16 + fx] = y;
        }
      }
    }
  }
}

extern "C" void kernel_launch(void* const* d_in, const int* in_sizes, int n_in,
                              void* d_out, int out_size, void* d_ws, size_t ws_size,
                              hipStream_t stream) {
  const float* pos   = (const float*)d_in[0];  // (4,4096,3)
  const float* W     = (const float*)d_in[1];  // (64,4096)
  const float* bias  = (const float*)d_in[2];  // (64,)
  const float* gamma = (const float*)d_in[3];  // (64,)
  const float* beta  = (const float*)d_in[4];  // (64,)
  float* out = (float*)d_out;                  // (4,4096,64)

  const size_t wb_bytes = (size_t)FEATD * N_PTS * sizeof(unsigned short);  // 512 KiB
  int use_ws = (d_ws != nullptr && ws_size >= wb_bytes);
  unsigned short* Wbt = use_ws ? (unsigned short*)d_ws : nullptr;

  if (use_ws) {
    wconv_kernel<<<dim3((FEATD * N_PTS / 8) / 256), dim3(256), 0, stream>>>(W, Wbt);
  }
  frp_kernel<<<dim3(256), dim3(1024), 0, stream>>>(pos, W, bias, gamma, beta, Wbt, out);
}